// Round 2
// baseline (217.669 us; speedup 1.0000x reference)
//
#include <hip/hip_runtime.h>
#include <stdint.h>

typedef __bf16 bf16_t;
typedef __bf16 bf16x8 __attribute__((ext_vector_type(8)));
typedef float  f32x4  __attribute__((ext_vector_type(4)));
typedef unsigned long long u64x2 __attribute__((ext_vector_type(2)));

#define SD 296          // LDS row stride in bf16 (288 data + 8 pad)
#define NPIX (8*64*64*64)

// ---------- weight repack (unchanged layout) ----------
// K global = ci*288 + fc*8 + j   [spline]
//          = ci*288 + 256 + fc   [silu/base]
// ci = 0..17: tap kpos = ci>>1, channel base c0 = (ci&1)*32, f = c*9 + kpos
__global__ __launch_bounds__(256) void prep_w_kernel(
    const float* __restrict__ bw, const float* __restrict__ sw,
    const float* __restrict__ ss, bf16_t* __restrict__ Wf) {
  int idx = blockIdx.x * 256 + threadIdx.x;
  if (idx >= 64 * 5184) return;
  int o  = idx / 5184;
  int kk = idx - o * 5184;
  int ci  = kk / 288;
  int loc = kk - ci * 288;
  int kpos = ci >> 1;
  int c0 = (ci & 1) * 32;
  float v;
  if (loc < 256) {
    int fc = loc >> 3; int j = loc & 7;
    int f = (c0 + fc) * 9 + kpos;
    v = sw[(o * 576 + f) * 8 + j] * ss[o * 576 + f];
  } else {
    int fc = loc - 256;
    int f = (c0 + fc) * 9 + kpos;
    v = bw[o * 576 + f];
  }
  Wf[idx] = (bf16_t)v;
}

// ---------- per-pixel precompute: spline window (8 bf16) + silu (1 bf16) ----------
__global__ __launch_bounds__(256) void precomp_kernel(
    const float* __restrict__ X, u64x2* __restrict__ spl8,
    bf16_t* __restrict__ sil) {
  int p = blockIdx.x * 256 + threadIdx.x;
  float x = X[p];

  const float h    = 0.4f;
  const float G0   = -3.0f * h - 1.0f;   // -2.2
  const float G1   =  8.0f * h - 1.0f;   //  2.2
  const float INVH = 1.0f / h;

  float sl = x / (1.0f + __expf(-x));

  float tt = (x - G0) * INVH;
  int  i0  = (int)tt;
  i0 = i0 < 0 ? 0 : (i0 > 10 ? 10 : i0);
  float u  = tt - (float)i0;
  float um = 1.0f - u;
  float u2 = u * u, u3 = u2 * u;
  float w0 = um * um * um * (1.0f / 6.0f);
  float w1 = (3.0f * u3 - 6.0f * u2 + 4.0f) * (1.0f / 6.0f);
  float w2 = (-3.0f * u3 + 3.0f * u2 + 3.0f * u + 1.0f) * (1.0f / 6.0f);
  float w3 = u3 * (1.0f / 6.0f);
  bool inr = (x >= G0) & (x < G1);

  union { bf16_t hh[4]; unsigned long long u64; } pk;
  pk.hh[0] = (bf16_t)w0; pk.hh[1] = (bf16_t)w1;
  pk.hh[2] = (bf16_t)w2; pk.hh[3] = (bf16_t)w3;
  unsigned long long a = inr ? pk.u64 : 0ull;

  int sh = (i0 - 3) * 16;
  unsigned long long lo, hi;
  if (sh >= 0) {
    lo = (sh < 64) ? (a << (sh & 63)) : 0ull;
    hi = (sh == 0) ? 0ull
         : ((sh < 64) ? (a >> ((64 - sh) & 63)) : (a << ((sh - 64) & 63)));
  } else {
    lo = a >> ((-sh) & 63);
    hi = 0ull;
  }
  u64x2 wr; wr.x = lo; wr.y = hi;
  spl8[p] = wr;
  sil[p]  = (bf16_t)sl;
}

// ---------- fused GEMM ----------
__global__ __launch_bounds__(256) void convkan_kernel(
    const u64x2* __restrict__ spl8, const bf16_t* __restrict__ sil,
    const bf16_t* __restrict__ Wf, float* __restrict__ out) {
  __shared__ bf16_t P[64 * SD];   // 37,888 B

  const int t    = threadIdx.x;
  const int lane = t & 63;
  const int wid  = t >> 6;
  const int n0   = blockIdx.x * 64;      // one output row (oh) per block
  const int bimg = n0 >> 12;
  const int oh0  = (n0 >> 6) & 63;

  const int fc = t >> 3;      // 0..31  channel-within-chunk
  const int wb = t & 7;       // row offset within stride-8 groups

  f32x4 acc[4];
  #pragma unroll
  for (int i = 0; i < 4; ++i) acc[i] = (f32x4)0.0f;

  const int rowRd = wid * 16 + (lane & 15);
  const int kRd   = (lane >> 4) * 8;

  for (int ci = 0; ci < 18; ++ci) {
    int kpos = ci >> 1;
    int ki = kpos / 3, kj = kpos - ki * 3;
    int c  = (ci & 1) * 32 + fc;
    int ih = oh0 + ki - 1;
    bool ihok = (ih >= 0) & (ih < 64);
    // base pixel index for this (channel, input row), at iw=0
    int pbase = ((bimg * 64 + c) * 64 + (ihok ? ih : 0)) * 64;

    #pragma unroll
    for (int r = 0; r < 8; ++r) {
      int row = r * 8 + wb;
      int iw  = row + kj - 1;
      bool ok = ihok & (iw >= 0) & (iw < 64);
      u64x2 w;
      bf16_t sl;
      if (ok) {
        w  = spl8[pbase + iw];
        sl = sil[pbase + iw];
      } else {
        // basis window of x=0: slots 2..5 = [1/48, 23/48, 23/48, 1/48] (bf16)
        w.x = 0x3EF53CAB00000000ull;
        w.y = 0x000000003CAB3EF5ull;
        sl  = (bf16_t)0.0f;
      }
      *(u64x2*)&P[row * SD + fc * 8] = w;
      P[row * SD + 256 + fc] = sl;
    }
    __syncthreads();

    // MFMA: K = 288 -> 9 steps of 32
    int kbase = ci * 288;
    bf16x8 afr[9];
    #pragma unroll
    for (int ks = 0; ks < 9; ++ks)
      afr[ks] = *(const bf16x8*)&P[rowRd * SD + ks * 32 + kRd];
    #pragma unroll
    for (int ks = 0; ks < 9; ++ks) {
      #pragma unroll
      for (int ot = 0; ot < 4; ++ot) {
        int o = ot * 16 + (lane & 15);
        bf16x8 bfrag = *(const bf16x8*)&Wf[o * 5184 + kbase + ks * 32 + kRd];
        acc[ot] = __builtin_amdgcn_mfma_f32_16x16x32_bf16(afr[ks], bfrag, acc[ot], 0, 0, 0);
      }
    }
    __syncthreads();
  }

  int nb   = n0 + wid * 16 + (lane >> 4) * 4;
  int nrem = nb & 4095;
  #pragma unroll
  for (int ot = 0; ot < 4; ++ot) {
    int o = ot * 16 + (lane & 15);
    *(f32x4*)&out[((bimg * 64 + o) << 12) + nrem] = acc[ot];
  }
}

extern "C" void kernel_launch(void* const* d_in, const int* in_sizes, int n_in,
                              void* d_out, int out_size, void* d_ws, size_t ws_size,
                              hipStream_t stream) {
  const float* x  = (const float*)d_in[0];
  const float* bw = (const float*)d_in[1];
  const float* sw = (const float*)d_in[2];
  const float* ss = (const float*)d_in[3];

  char* ws = (char*)d_ws;
  bf16_t* Wf   = (bf16_t*)ws;                         // 663,552 B
  u64x2*  spl8 = (u64x2*)(ws + 663552);               // 33,554,432 B
  bf16_t* sil  = (bf16_t*)(ws + 663552 + (size_t)NPIX * 16);  // 4,194,304 B
  float* o = (float*)d_out;

  prep_w_kernel<<<(64 * 5184 + 255) / 256, 256, 0, stream>>>(bw, sw, ss, Wf);
  precomp_kernel<<<NPIX / 256, 256, 0, stream>>>(x, spl8, sil);
  convkan_kernel<<<512, 256, 0, stream>>>(spl8, sil, Wf, o);
}

// Round 3
// 175.399 us; speedup vs baseline: 1.2410x; 1.2410x over previous
//
#include <hip/hip_runtime.h>
#include <stdint.h>

typedef __bf16 bf16_t;
typedef __bf16 bf16x8 __attribute__((ext_vector_type(8)));
typedef float  f32x4  __attribute__((ext_vector_type(4)));

// ---------------- weight repack ----------------
// K layout (total 5184):
//   spline: k = (tap*64 + c)*8 + j     k in [0,4608), tap=ki*3+kj in 0..8
//   silu:   k = 4608 + tap*64 + c
// reference f = c*9 + tap
__global__ __launch_bounds__(256) void prep_w_kernel(
    const float* __restrict__ bw, const float* __restrict__ sw,
    const float* __restrict__ ss, bf16_t* __restrict__ Wf) {
  int idx = blockIdx.x * 256 + threadIdx.x;
  if (idx >= 64 * 5184) return;
  int o = idx / 5184;
  int k = idx - o * 5184;
  float v;
  if (k < 4608) {
    int j = k & 7;
    int q = k >> 3;           // tap*64 + c
    int tap = q >> 6;
    int c = q & 63;
    int f = c * 9 + tap;
    v = sw[(o * 576 + f) * 8 + j] * ss[o * 576 + f];
  } else {
    int k2 = k - 4608;
    int tap = k2 >> 6;
    int c = k2 & 63;
    int f = c * 9 + tap;
    v = bw[o * 576 + f];
  }
  Wf[idx] = (bf16_t)v;
}

// ---------------- fused conv-KAN GEMM, A built in registers ----------------
__global__ __launch_bounds__(512, 2) void convkan_kernel(
    const float* __restrict__ X, const bf16_t* __restrict__ Wf,
    float* __restrict__ out) {
  __shared__ float red[4][32][65];   // 33,280 B  (K-split reduction)

  const int t    = threadIdx.x;
  const int lane = t & 63;
  const int w    = t >> 6;    // 0..7
  const int g    = w & 3;     // row-group
  const int hh   = w >> 2;    // K-half (by step parity)
  const int lrow = lane & 15;
  const int lk   = lane >> 4; // 0..3

  const int n0   = blockIdx.x * 128;          // 128 rows = 2 output rows
  const int bimg = n0 >> 12;
  const int oh   = ((n0 >> 6) & 63) + (g >> 1);
  const int ow0  = (g & 1) * 32;

  const float* Xb = X + (((size_t)bimg) << 18);   // image base (64*4096 floats)

  const float G0   = -2.2f;
  const float G1   =  2.2f;
  const float INVH =  2.5f;

  f32x4 acc[2][4];
  #pragma unroll
  for (int a = 0; a < 2; ++a)
    #pragma unroll
    for (int b = 0; b < 4; ++b) acc[a][b] = (f32x4)0.0f;

  // ---- spline K region: 144 k-steps, this wave takes parity hh (72 steps) ----
  for (int i = 0; i < 72; ++i) {
    int s   = 2 * i + hh;
    int tap = s >> 4;
    int cb  = (s & 15) * 4;
    int c   = cb + lk;
    int ki  = tap / 3;
    int kj  = tap - ki * 3;
    int ih  = oh + ki - 1;
    bool ihok = ((unsigned)ih < 64u);
    const float* Xrow = Xb + ((size_t)c << 12) + ((ihok ? ih : 0) << 6);

    bf16x8 afr[2];
    #pragma unroll
    for (int rt = 0; rt < 2; ++rt) {
      int iw  = ow0 + rt * 16 + lrow + kj - 1;
      bool ok = ihok & ((unsigned)iw < 64u);
      float xv = Xrow[ok ? iw : 0];
      float x  = ok ? xv : 0.0f;

      // uniform cubic B-spline window (4 nonzero taps), packed at slot i0-3
      float tt = (x - G0) * INVH;
      int  i0  = (int)tt;
      i0 = i0 < 0 ? 0 : (i0 > 10 ? 10 : i0);
      float u  = tt - (float)i0;
      float um = 1.0f - u;
      float u2 = u * u, u3 = u2 * u;
      float w0 = um * um * um * (1.0f / 6.0f);
      float w1 = (3.0f * u3 - 6.0f * u2 + 4.0f) * (1.0f / 6.0f);
      float w2 = (-3.0f * u3 + 3.0f * u2 + 3.0f * u + 1.0f) * (1.0f / 6.0f);
      float w3 = u3 * (1.0f / 6.0f);
      bool inr = (x >= G0) & (x < G1);

      union { bf16_t hh4[4]; unsigned long long u64; } pk;
      pk.hh4[0] = (bf16_t)w0; pk.hh4[1] = (bf16_t)w1;
      pk.hh4[2] = (bf16_t)w2; pk.hh4[3] = (bf16_t)w3;
      unsigned long long a = inr ? pk.u64 : 0ull;

      int sh = (i0 - 3) * 16;
      unsigned long long lo, hi;
      if (sh >= 0) {
        lo = (sh < 64) ? (a << (sh & 63)) : 0ull;
        hi = (sh == 0) ? 0ull
             : ((sh < 64) ? (a >> ((64 - sh) & 63)) : (a << ((sh - 64) & 63)));
      } else {
        lo = a >> ((-sh) & 63);
        hi = 0ull;
      }
      union { unsigned long long q[2]; bf16x8 v; } W;
      W.q[0] = lo; W.q[1] = hi;
      afr[rt] = W.v;
    }

    int kb = s * 32 + lk * 8;
    #pragma unroll
    for (int ot = 0; ot < 4; ++ot) {
      int o = ot * 16 + lrow;
      bf16x8 bfr = *(const bf16x8*)&Wf[o * 5184 + kb];
      acc[0][ot] = __builtin_amdgcn_mfma_f32_16x16x32_bf16(afr[0], bfr, acc[0][ot], 0, 0, 0);
      acc[1][ot] = __builtin_amdgcn_mfma_f32_16x16x32_bf16(afr[1], bfr, acc[1][ot], 0, 0, 0);
    }
  }

  // ---- silu K region: 18 k-steps, parity split (9 steps) ----
  for (int i = 0; i < 9; ++i) {
    int ts  = 2 * i + hh;
    int tap = ts >> 1;
    int ki  = tap / 3;
    int kj  = tap - ki * 3;
    int ih  = oh + ki - 1;
    bool ihok = ((unsigned)ih < 64u);
    int ihc = ihok ? ih : 0;
    int c8  = (ts & 1) * 32 + lk * 8;

    bf16x8 afr[2];
    #pragma unroll
    for (int rt = 0; rt < 2; ++rt) {
      int iw  = ow0 + rt * 16 + lrow + kj - 1;
      bool ok = ihok & ((unsigned)iw < 64u);
      int iwc = ok ? iw : 0;
      union { bf16_t hh8[8]; bf16x8 v; } pk;
      #pragma unroll
      for (int j = 0; j < 8; ++j) {
        float xv = Xb[(((size_t)(c8 + j)) << 12) + (ihc << 6) + iwc];
        float x  = ok ? xv : 0.0f;
        float sl = x / (1.0f + __expf(-x));
        pk.hh8[j] = (bf16_t)sl;
      }
      afr[rt] = pk.v;
    }

    int kb = 4608 + ts * 32 + lk * 8;
    #pragma unroll
    for (int ot = 0; ot < 4; ++ot) {
      int o = ot * 16 + lrow;
      bf16x8 bfr = *(const bf16x8*)&Wf[o * 5184 + kb];
      acc[0][ot] = __builtin_amdgcn_mfma_f32_16x16x32_bf16(afr[0], bfr, acc[0][ot], 0, 0, 0);
      acc[1][ot] = __builtin_amdgcn_mfma_f32_16x16x32_bf16(afr[1], bfr, acc[1][ot], 0, 0, 0);
    }
  }

  // ---- K-split reduction: h=1 waves dump to LDS, h=0 waves combine+store ----
  if (hh == 1) {
    #pragma unroll
    for (int rt = 0; rt < 2; ++rt)
      #pragma unroll
      for (int ot = 0; ot < 4; ++ot)
        #pragma unroll
        for (int q = 0; q < 4; ++q)
          red[g][rt * 16 + lk * 4 + q][ot * 16 + lrow] = acc[rt][ot][q];
  }
  __syncthreads();
  if (hh == 0) {
    #pragma unroll
    for (int rt = 0; rt < 2; ++rt) {
      int nw   = n0 + g * 32 + rt * 16 + lk * 4;
      int nrem = nw & 4095;
      #pragma unroll
      for (int ot = 0; ot < 4; ++ot) {
        int o = ot * 16 + lrow;
        f32x4 v = acc[rt][ot];
        #pragma unroll
        for (int q = 0; q < 4; ++q)
          v[q] += red[g][rt * 16 + lk * 4 + q][ot * 16 + lrow];
        *(f32x4*)&out[(((size_t)(bimg * 64 + o)) << 12) + nrem] = v;
      }
    }
  }
}

extern "C" void kernel_launch(void* const* d_in, const int* in_sizes, int n_in,
                              void* d_out, int out_size, void* d_ws, size_t ws_size,
                              hipStream_t stream) {
  const float* x  = (const float*)d_in[0];
  const float* bw = (const float*)d_in[1];
  const float* sw = (const float*)d_in[2];
  const float* ss = (const float*)d_in[3];

  bf16_t* Wf = (bf16_t*)d_ws;            // 64*5184*2 = 663,552 B
  float* o   = (float*)d_out;

  prep_w_kernel<<<(64 * 5184 + 255) / 256, 256, 0, stream>>>(bw, sw, ss, Wf);
  convkan_kernel<<<256, 512, 0, stream>>>(x, Wf, o);
}

// Round 5
// 139.956 us; speedup vs baseline: 1.5553x; 1.2532x over previous
//
#include <hip/hip_runtime.h>
#include <stdint.h>

typedef __bf16 bf16_t;
typedef __bf16 bf16x8 __attribute__((ext_vector_type(8)));
typedef float  f32x4  __attribute__((ext_vector_type(4)));
typedef float  f32x16 __attribute__((ext_vector_type(16)));

// ws layout
#define WF_OFF    0u
#define SPL_OFF   1048576u                  // 64*8 planes * 4356 cells * 16B = 35,684,352
#define SILT_OFF  (1048576u + 35684352u)    // 8*4356*64*2B = 4,460,544

// ---------------- weight repack (same K-order as R3, verified) ----------------
// spline: k = tap*512 + c*8 + j ; silu: k = 4608 + tap*64 + c ; f = c*9 + tap
__global__ __launch_bounds__(256) void prep_w_kernel(
    const float* __restrict__ bw, const float* __restrict__ sw,
    const float* __restrict__ ss, bf16_t* __restrict__ Wf) {
  int idx = blockIdx.x * 256 + threadIdx.x;
  if (idx >= 64 * 5184) return;
  int o = idx / 5184;
  int k = idx - o * 5184;
  float v;
  if (k < 4608) {
    int j = k & 7;
    int q = k >> 3;           // tap*64 + c
    int tap = q >> 6;
    int c = q & 63;
    int f = c * 9 + tap;
    v = sw[(o * 576 + f) * 8 + j] * ss[o * 576 + f];
  } else {
    int k2 = k - 4608;
    int tap = k2 >> 6;
    int c = k2 & 63;
    int f = c * 9 + tap;
    v = bw[o * 576 + f];
  }
  Wf[idx] = (bf16_t)v;
}

// ---------------- per-pixel precompute into PADDED layouts ----------------
// spl8: [bimg*64+c][ihp 0..65][iwp 0..65] uint4 (8 bf16 window)
// silT: [bimg][ihp][iwp][c 0..63] bf16     (silu, channel-contiguous)
__global__ __launch_bounds__(256) void precomp_kernel(
    const float* __restrict__ X, uint4* __restrict__ spl8,
    bf16_t* __restrict__ silT) {
  __shared__ bf16_t trans[64 * 72];
  const int t = threadIdx.x;
  const int bb = blockIdx.x;          // 512: (bimg, ih)
  const int bimg = bb >> 6, ih = bb & 63;
  const int iw = t & 63;
  const int c4 = t >> 6;

  const float* Xp = X + (((size_t)bimg * 64) << 12) + (ih << 6);

  const float G0 = -2.2f, G1 = 2.2f, INVH = 2.5f;

  for (int q = 0; q < 16; ++q) {
    int c = c4 * 16 + q;
    float x = Xp[((size_t)c << 12) + iw];

    float sl = x / (1.0f + __expf(-x));

    float tt = (x - G0) * INVH;
    int i0 = (int)tt;
    i0 = i0 < 0 ? 0 : (i0 > 10 ? 10 : i0);
    float u  = tt - (float)i0;
    float um = 1.0f - u;
    float u2 = u * u, u3 = u2 * u;
    float w0 = um * um * um * (1.0f / 6.0f);
    float w1 = (3.0f * u3 - 6.0f * u2 + 4.0f) * (1.0f / 6.0f);
    float w2 = (-3.0f * u3 + 3.0f * u2 + 3.0f * u + 1.0f) * (1.0f / 6.0f);
    float w3 = u3 * (1.0f / 6.0f);
    bool inr = (x >= G0) & (x < G1);

    union { bf16_t hh4[4]; unsigned long long u64; } pk;
    pk.hh4[0] = (bf16_t)w0; pk.hh4[1] = (bf16_t)w1;
    pk.hh4[2] = (bf16_t)w2; pk.hh4[3] = (bf16_t)w3;
    unsigned long long a = inr ? pk.u64 : 0ull;

    int sh = (i0 - 3) * 16;
    unsigned long long lo, hi;
    if (sh >= 0) {
      lo = (sh < 64) ? (a << (sh & 63)) : 0ull;
      hi = (sh == 0) ? 0ull
           : ((sh < 64) ? (a >> ((64 - sh) & 63)) : (a << ((sh - 64) & 63)));
    } else {
      lo = a >> ((-sh) & 63);
      hi = 0ull;
    }
    uint4 wv;
    wv.x = (unsigned)(lo & 0xffffffffull); wv.y = (unsigned)(lo >> 32);
    wv.z = (unsigned)(hi & 0xffffffffull); wv.w = (unsigned)(hi >> 32);
    spl8[(size_t)(bimg * 64 + c) * 4356 + (ih + 1) * 66 + (iw + 1)] = wv;

    trans[iw * 72 + c] = (bf16_t)sl;
  }
  __syncthreads();
  #pragma unroll
  for (int p = 0; p < 2; ++p) {
    int iw2 = (t >> 3) + p * 32;
    int c8  = (t & 7) * 8;
    bf16x8 v = *(const bf16x8*)&trans[iw2 * 72 + c8];
    *(bf16x8*)&silT[((size_t)(bimg * 4356 + (ih + 1) * 66 + (iw2 + 1)) << 6) + c8] = v;
  }
}

// ---------------- border fill: x=0 window / silu 0 ----------------
// 260 border cells per plane; grid-stride so 256 threads cover all of them.
__global__ __launch_bounds__(256) void fill_border_kernel(
    uint4* __restrict__ spl8, bf16_t* __restrict__ silT) {
  const int b = blockIdx.x;   // 0..511: spl8 plane ; 512..519: silT image
  for (int s = threadIdx.x; s < 260; s += 256) {
    int ihp, iwp;
    if (s < 66)       { ihp = 0;        iwp = s; }
    else if (s < 132) { ihp = 65;       iwp = s - 66; }
    else if (s < 196) { ihp = s - 131;  iwp = 0; }    // 1..64
    else              { ihp = s - 195;  iwp = 65; }   // 1..64
    if (b < 512) {
      uint4 cw; cw.x = 0u; cw.y = 0x3EF53CABu; cw.z = 0x3CAB3EF5u; cw.w = 0u;
      spl8[(size_t)b * 4356 + ihp * 66 + iwp] = cw;
    } else {
      int img = b - 512;
      uint4 z; z.x = z.y = z.z = z.w = 0u;
      size_t base = ((size_t)(img * 4356 + ihp * 66 + iwp) << 6);
      #pragma unroll
      for (int j = 0; j < 8; ++j)
        *(uint4*)&silT[base + j * 8] = z;
    }
  }
}

// ---------------- main fused GEMM: A = one dwordx4, 32x32x16 MFMA ----------------
__global__ __launch_bounds__(256, 4) void convkan_kernel(
    const uint4* __restrict__ spl8, const bf16_t* __restrict__ silT,
    const bf16_t* __restrict__ Wf, float* __restrict__ out) {
  __shared__ float red[2][32][33];   // 8448 B

  const int t    = threadIdx.x;
  const int lane = t & 63;
  const int w4   = t >> 6;
  const int par  = w4 & 1;          // K-split parity
  const int col  = w4 >> 1;         // out-ch half
  const int r    = lane & 31;       // A row (ow) / B col (o)
  const int kh   = lane >> 5;       // k-half within 16-step

  const int b    = blockIdx.x;
  const int rb   = ((b & 7) << 7) | (b >> 3);   // XCD-chunked, bijective (1024%8==0)
  const int bimg = rb >> 7;
  const int oh   = (rb & 127) >> 1;
  const int ow0  = (rb & 1) << 5;

  f32x16 acc = (f32x16)0.0f;

  // A: c = 4*ti + 2*par + kh
  const uint4* abase = spl8 + (size_t)(bimg * 64 + 2 * par + kh) * 4356;
  // B: k = tap*512 + ti*32 + par*16 + kh*8 (+j)
  const bf16_t* bbase = Wf + (size_t)(col * 32 + r) * 5184 + par * 16 + kh * 8;

  #pragma unroll
  for (int tap = 0; tap < 9; ++tap) {
    const int ki = tap / 3, kj = tap % 3;
    const uint4*  ap = abase + (oh + ki) * 66 + (ow0 + r + kj);
    const bf16_t* bp = bbase + tap * 512;
    #pragma unroll
    for (int ti = 0; ti < 16; ++ti) {
      union { uint4 u; bf16x8 v; } A;
      A.u = ap[(size_t)ti * 17424];           // stride 4 channels * 4356 cells
      bf16x8 B = *(const bf16x8*)(bp + ti * 32);
      acc = __builtin_amdgcn_mfma_f32_32x32x16_bf16(A.v, B, acc, 0, 0, 0);
    }
  }

  // silu region: 36 steps of K=16, this wave: u = 2*ui + par
  #pragma unroll
  for (int ui = 0; ui < 18; ++ui) {
    const int u   = 2 * ui + par;
    const int tap = u >> 2;
    const int ki  = tap / 3, kj = tap % 3;
    const int c0  = (u & 3) * 16 + kh * 8;
    const bf16_t* apx = silT +
        ((size_t)(bimg * 4356 + (oh + ki) * 66 + (ow0 + r + kj)) << 6) + c0;
    bf16x8 A = *(const bf16x8*)apx;
    bf16x8 B = *(const bf16x8*)(bbase - par * 16 + 4608 + u * 16);
    acc = __builtin_amdgcn_mfma_f32_32x32x16_bf16(A, B, acc, 0, 0, 0);
  }

  // K-split combine (par 1 -> LDS, par 0 adds and stores)
  if (par == 1) {
    #pragma unroll
    for (int q = 0; q < 16; ++q) {
      int ro = (q & 3) + 8 * (q >> 2) + 4 * kh;
      red[col][ro][r] = acc[q];
    }
  }
  __syncthreads();
  if (par == 0) {
    const int O = col * 32 + r;
    float* ob = out + (((size_t)(bimg * 64 + O)) << 12) + oh * 64 + ow0;
    #pragma unroll
    for (int g2 = 0; g2 < 4; ++g2) {
      f32x4 v;
      #pragma unroll
      for (int i = 0; i < 4; ++i) {
        int ro = i + 8 * g2 + 4 * kh;
        v[i] = acc[g2 * 4 + i] + red[col][ro][r];
      }
      *(f32x4*)(ob + 8 * g2 + 4 * kh) = v;
    }
  }
}

extern "C" void kernel_launch(void* const* d_in, const int* in_sizes, int n_in,
                              void* d_out, int out_size, void* d_ws, size_t ws_size,
                              hipStream_t stream) {
  const float* x  = (const float*)d_in[0];
  const float* bw = (const float*)d_in[1];
  const float* sw = (const float*)d_in[2];
  const float* ss = (const float*)d_in[3];

  char* ws = (char*)d_ws;
  bf16_t* Wf   = (bf16_t*)(ws + WF_OFF);
  uint4*  spl8 = (uint4*)(ws + SPL_OFF);
  bf16_t* silT = (bf16_t*)(ws + SILT_OFF);
  float*  o    = (float*)d_out;

  prep_w_kernel<<<(64 * 5184 + 255) / 256, 256, 0, stream>>>(bw, sw, ss, Wf);
  precomp_kernel<<<512, 256, 0, stream>>>(x, spl8, silT);
  fill_border_kernel<<<520, 256, 0, stream>>>(spl8, silT);
  convkan_kernel<<<1024, 256, 0, stream>>>(spl8, silT, Wf, o);
}

// Round 6
// 90.721 us; speedup vs baseline: 2.3993x; 1.5427x over previous
//
#include <hip/hip_runtime.h>
#include <stdint.h>

typedef __bf16 bf16_t;
typedef __bf16 bf16x8 __attribute__((ext_vector_type(8)));
typedef float  f32x4  __attribute__((ext_vector_type(4)));
typedef float  f32x16 __attribute__((ext_vector_type(16)));

// ws layout
#define WF_OFF    0u
#define SPL_OFF   1048576u                  // 64*8 planes * 4356 cells * 16B = 35,684,352
#define SILT_OFF  (1048576u + 35684352u)    // 8*4356*64*2B = 4,460,544

// ---------------- weight repack into step-major layout ----------------
// Wf2[s][o][kk], s=0..323, o=0..63, kk=kh*8+j (16 bf16 per (s,o))
// spline steps s = q*9 + tap (q=0..31 channel-pair, tap=0..8): c = q*2+kh, f = c*9+tap
// silu steps   s = 288 + cq*9 + tap (cq=0..3): c = cq*16+kk, f = c*9+tap
__global__ __launch_bounds__(256) void prep_w_kernel(
    const float* __restrict__ bw, const float* __restrict__ sw,
    const float* __restrict__ ss, bf16_t* __restrict__ Wf2) {
  int idx = blockIdx.x * 256 + threadIdx.x;   // < 324*64*16 = 331776
  int kk = idx & 15, o = (idx >> 4) & 63, s = idx >> 10;
  int kh = kk >> 3, j = kk & 7;
  float v;
  if (s < 288) {
    int q = s / 9, tap = s - q * 9;
    int c = q * 2 + kh;
    int f = c * 9 + tap;
    v = sw[(o * 576 + f) * 8 + j] * ss[o * 576 + f];
  } else {
    int t2 = s - 288;
    int cq = t2 / 9, tap = t2 - cq * 9;
    int c = cq * 16 + kk;
    int f = c * 9 + tap;
    v = bw[o * 576 + f];
  }
  Wf2[idx] = (bf16_t)v;
}

// ---------------- per-pixel precompute into PADDED layouts ----------------
// spl8: [bimg*64+c][ihp 0..65][iwp 0..65] uint4 (8 bf16 window)
// silT: [bimg][ihp][iwp][c 0..63] bf16     (silu, channel-contiguous)
__global__ __launch_bounds__(256) void precomp_kernel(
    const float* __restrict__ X, uint4* __restrict__ spl8,
    bf16_t* __restrict__ silT) {
  __shared__ bf16_t trans[64 * 72];
  const int t = threadIdx.x;
  const int bb = blockIdx.x;          // 512: (bimg, ih)
  const int bimg = bb >> 6, ih = bb & 63;
  const int iw = t & 63;
  const int c4 = t >> 6;

  const float* Xp = X + (((size_t)bimg * 64) << 12) + (ih << 6);

  const float G0 = -2.2f, G1 = 2.2f, INVH = 2.5f;

  for (int q = 0; q < 16; ++q) {
    int c = c4 * 16 + q;
    float x = Xp[((size_t)c << 12) + iw];

    float sl = x / (1.0f + __expf(-x));

    float tt = (x - G0) * INVH;
    int i0 = (int)tt;
    i0 = i0 < 0 ? 0 : (i0 > 10 ? 10 : i0);
    float u  = tt - (float)i0;
    float um = 1.0f - u;
    float u2 = u * u, u3 = u2 * u;
    float w0 = um * um * um * (1.0f / 6.0f);
    float w1 = (3.0f * u3 - 6.0f * u2 + 4.0f) * (1.0f / 6.0f);
    float w2 = (-3.0f * u3 + 3.0f * u2 + 3.0f * u + 1.0f) * (1.0f / 6.0f);
    float w3 = u3 * (1.0f / 6.0f);
    bool inr = (x >= G0) & (x < G1);

    union { bf16_t hh4[4]; unsigned long long u64; } pk;
    pk.hh4[0] = (bf16_t)w0; pk.hh4[1] = (bf16_t)w1;
    pk.hh4[2] = (bf16_t)w2; pk.hh4[3] = (bf16_t)w3;
    unsigned long long a = inr ? pk.u64 : 0ull;

    int sh = (i0 - 3) * 16;
    unsigned long long lo, hi;
    if (sh >= 0) {
      lo = (sh < 64) ? (a << (sh & 63)) : 0ull;
      hi = (sh == 0) ? 0ull
           : ((sh < 64) ? (a >> ((64 - sh) & 63)) : (a << ((sh - 64) & 63)));
    } else {
      lo = a >> ((-sh) & 63);
      hi = 0ull;
    }
    uint4 wv;
    wv.x = (unsigned)(lo & 0xffffffffull); wv.y = (unsigned)(lo >> 32);
    wv.z = (unsigned)(hi & 0xffffffffull); wv.w = (unsigned)(hi >> 32);
    spl8[(size_t)(bimg * 64 + c) * 4356 + (ih + 1) * 66 + (iw + 1)] = wv;

    trans[iw * 72 + c] = (bf16_t)sl;
  }
  __syncthreads();
  #pragma unroll
  for (int p = 0; p < 2; ++p) {
    int iw2 = (t >> 3) + p * 32;
    int c8  = (t & 7) * 8;
    bf16x8 v = *(const bf16x8*)&trans[iw2 * 72 + c8];
    *(bf16x8*)&silT[((size_t)(bimg * 4356 + (ih + 1) * 66 + (iw2 + 1)) << 6) + c8] = v;
  }
}

// ---------------- border fill: x=0 window / silu 0 (grid-stride, 260 cells) ----------------
__global__ __launch_bounds__(256) void fill_border_kernel(
    uint4* __restrict__ spl8, bf16_t* __restrict__ silT) {
  const int b = blockIdx.x;   // 0..511: spl8 plane ; 512..519: silT image
  for (int s = threadIdx.x; s < 260; s += 256) {
    int ihp, iwp;
    if (s < 66)       { ihp = 0;        iwp = s; }
    else if (s < 132) { ihp = 65;       iwp = s - 66; }
    else if (s < 196) { ihp = s - 131;  iwp = 0; }    // 1..64
    else              { ihp = s - 195;  iwp = 65; }   // 1..64
    if (b < 512) {
      uint4 cw; cw.x = 0u; cw.y = 0x3EF53CABu; cw.z = 0x3CAB3EF5u; cw.w = 0u;
      spl8[(size_t)b * 4356 + ihp * 66 + iwp] = cw;
    } else {
      int img = b - 512;
      uint4 z; z.x = z.y = z.z = z.w = 0u;
      size_t base = ((size_t)(img * 4356 + ihp * 66 + iwp) << 6);
      #pragma unroll
      for (int j = 0; j < 8; ++j)
        *(uint4*)&silT[base + j * 8] = z;
    }
  }
}

// ---------------- main fused GEMM ----------------
// block = 32 px (4 oh x 8 ow) x 32 out-ch; 4 waves = 4-way contiguous K-split.
// grid 2048: 8 img x 16 ohb x 8 owb x 2 colh. 8 blocks/CU -> 32 waves/CU.
__global__ __launch_bounds__(256, 8) void convkan_kernel(
    const uint4* __restrict__ spl8, const bf16_t* __restrict__ silT,
    const bf16_t* __restrict__ Wf2, float* __restrict__ out) {
  __shared__ float red[3][32][33];   // 12,672 B

  const int t    = threadIdx.x;
  const int lane = t & 63;
  const int par  = t >> 6;          // K-split 0..3
  const int r    = lane & 31;       // A-row (pixel) / B-col (out-ch)
  const int kh   = lane >> 5;       // k-half

  const int b  = blockIdx.x;
  const int rb = ((b & 7) << 8) | (b >> 3);   // XCD-chunked: 1 image per XCD
  const int img  = rb >> 8;
  const int rem  = rb & 255;
  const int colh = rem & 1;
  const int owb  = (rem >> 1) & 7;
  const int ohb  = rem >> 4;

  const int poh = r >> 3, pw = r & 7;
  const int arow = (ohb * 4 + poh) * 66 + owb * 8 + pw;  // padded (ihp,iwp) at ki=kj=0

  f32x16 acc = (f32x16)0.0f;

  // A: channel c = par*16 + qq*2 + kh
  const uint4* ac = spl8 + ((size_t)(img * 64 + par * 16 + kh)) * 4356 + arow;
  // B: per-lane base within a step's 2KB chunk
  const bf16_t* bb = Wf2 + (colh * 32 + r) * 16 + kh * 8;

  for (int qq = 0; qq < 8; ++qq) {
    const uint4*  aq = ac + (size_t)qq * 2 * 4356;
    const bf16_t* bq = bb + (size_t)(par * 72 + qq * 9) * 1024;
    #pragma unroll
    for (int tap = 0; tap < 9; ++tap) {
      const int ki = tap / 3, kj = tap % 3;
      union { uint4 u; bf16x8 v; } A;
      A.u = aq[ki * 66 + kj];
      bf16x8 B = *(const bf16x8*)(bq + tap * 1024);
      acc = __builtin_amdgcn_mfma_f32_32x32x16_bf16(A.v, B, acc, 0, 0, 0);
    }
  }

  // silu region: this wave handles channel-quad cq = par, taps 0..8
  {
    const bf16_t* sb = silT + (((size_t)(img * 4356) + arow) << 6) + par * 16 + kh * 8;
    const bf16_t* bq = bb + (size_t)(288 + par * 9) * 1024;
    #pragma unroll
    for (int tap = 0; tap < 9; ++tap) {
      const int ki = tap / 3, kj = tap % 3;
      bf16x8 A = *(const bf16x8*)(sb + ((ki * 66 + kj) << 6));
      bf16x8 B = *(const bf16x8*)(bq + tap * 1024);
      acc = __builtin_amdgcn_mfma_f32_32x32x16_bf16(A, B, acc, 0, 0, 0);
    }
  }

  // 4-way K-split combine
  if (par != 0) {
    #pragma unroll
    for (int q = 0; q < 16; ++q) {
      int ro = (q & 3) + 8 * (q >> 2) + 4 * kh;
      red[par - 1][ro][r] = acc[q];
    }
  }
  __syncthreads();
  if (par == 0) {
    const int o = colh * 32 + r;
    float* ob = out + (((size_t)(img * 64 + o)) << 12) + (ohb * 4) * 64 + owb * 8 + 4 * kh;
    #pragma unroll
    for (int g = 0; g < 4; ++g) {
      f32x4 v;
      #pragma unroll
      for (int i = 0; i < 4; ++i) {
        int ro = i + 8 * g + 4 * kh;
        v[i] = acc[g * 4 + i] + red[0][ro][r] + red[1][ro][r] + red[2][ro][r];
      }
      *(f32x4*)(ob + g * 64) = v;
    }
  }
}

extern "C" void kernel_launch(void* const* d_in, const int* in_sizes, int n_in,
                              void* d_out, int out_size, void* d_ws, size_t ws_size,
                              hipStream_t stream) {
  const float* x  = (const float*)d_in[0];
  const float* bw = (const float*)d_in[1];
  const float* sw = (const float*)d_in[2];
  const float* ss = (const float*)d_in[3];

  char* ws = (char*)d_ws;
  bf16_t* Wf2  = (bf16_t*)(ws + WF_OFF);
  uint4*  spl8 = (uint4*)(ws + SPL_OFF);
  bf16_t* silT = (bf16_t*)(ws + SILT_OFF);
  float*  o    = (float*)d_out;

  prep_w_kernel<<<1296, 256, 0, stream>>>(bw, sw, ss, Wf2);
  precomp_kernel<<<512, 256, 0, stream>>>(x, spl8, silT);
  fill_border_kernel<<<520, 256, 0, stream>>>(spl8, silT);
  convkan_kernel<<<2048, 256, 0, stream>>>(spl8, silT, Wf2, o);
}

// Round 7
// 67.296 us; speedup vs baseline: 3.2345x; 1.3481x over previous
//
#include <hip/hip_runtime.h>
#include <stdint.h>

typedef __bf16 bf16_t;
typedef __bf16 bf16x8 __attribute__((ext_vector_type(8)));
typedef float  f32x4  __attribute__((ext_vector_type(4)));
typedef float  f32x16 __attribute__((ext_vector_type(16)));

// ws layout
#define WF_OFF    0u
#define SPL_OFF   1048576u                  // 64*8 planes * 4356 cells * 16B = 35,684,352
#define SILT_OFF  (1048576u + 35684352u)    // 8*4356*64*2B = 4,460,544

// ---------------- weight repack into step-major layout ----------------
// Wf2[s][o][kk], s=0..323, o=0..63, kk=kh*8+j (16 bf16 per (s,o))
// spline steps s = q*9 + tap (q=0..31 channel-pair, tap=0..8): c = q*2+kh, f = c*9+tap
// silu steps   s = 288 + cq*9 + tap (cq=0..3): c = cq*16+kk, f = c*9+tap
__global__ __launch_bounds__(256) void prep_w_kernel(
    const float* __restrict__ bw, const float* __restrict__ sw,
    const float* __restrict__ ss, bf16_t* __restrict__ Wf2) {
  int idx = blockIdx.x * 256 + threadIdx.x;   // < 324*64*16 = 331776
  int kk = idx & 15, o = (idx >> 4) & 63, s = idx >> 10;
  int kh = kk >> 3, j = kk & 7;
  float v;
  if (s < 288) {
    int q = s / 9, tap = s - q * 9;
    int c = q * 2 + kh;
    int f = c * 9 + tap;
    v = sw[(o * 576 + f) * 8 + j] * ss[o * 576 + f];
  } else {
    int t2 = s - 288;
    int cq = t2 / 9, tap = t2 - cq * 9;
    int c = cq * 16 + kk;
    int f = c * 9 + tap;
    v = bw[o * 576 + f];
  }
  Wf2[idx] = (bf16_t)v;
}

// ---------------- per-pixel precompute into PADDED layouts ----------------
// spl8: [bimg*64+c][ihp 0..65][iwp 0..65] uint4 (8 bf16 window)
// silT: [bimg][ihp][iwp][c 0..63] bf16     (silu, channel-contiguous)
__global__ __launch_bounds__(256) void precomp_kernel(
    const float* __restrict__ X, uint4* __restrict__ spl8,
    bf16_t* __restrict__ silT) {
  __shared__ bf16_t trans[64 * 72];
  const int t = threadIdx.x;
  const int bb = blockIdx.x;          // 512: (bimg, ih)
  const int bimg = bb >> 6, ih = bb & 63;
  const int iw = t & 63;
  const int c4 = t >> 6;

  const float* Xp = X + (((size_t)bimg * 64) << 12) + (ih << 6);

  const float G0 = -2.2f, G1 = 2.2f, INVH = 2.5f;

  for (int q = 0; q < 16; ++q) {
    int c = c4 * 16 + q;
    float x = Xp[((size_t)c << 12) + iw];

    float sl = x / (1.0f + __expf(-x));

    float tt = (x - G0) * INVH;
    int i0 = (int)tt;
    i0 = i0 < 0 ? 0 : (i0 > 10 ? 10 : i0);
    float u  = tt - (float)i0;
    float um = 1.0f - u;
    float u2 = u * u, u3 = u2 * u;
    float w0 = um * um * um * (1.0f / 6.0f);
    float w1 = (3.0f * u3 - 6.0f * u2 + 4.0f) * (1.0f / 6.0f);
    float w2 = (-3.0f * u3 + 3.0f * u2 + 3.0f * u + 1.0f) * (1.0f / 6.0f);
    float w3 = u3 * (1.0f / 6.0f);
    bool inr = (x >= G0) & (x < G1);

    union { bf16_t hh4[4]; unsigned long long u64; } pk;
    pk.hh4[0] = (bf16_t)w0; pk.hh4[1] = (bf16_t)w1;
    pk.hh4[2] = (bf16_t)w2; pk.hh4[3] = (bf16_t)w3;
    unsigned long long a = inr ? pk.u64 : 0ull;

    int sh = (i0 - 3) * 16;
    unsigned long long lo, hi;
    if (sh >= 0) {
      lo = (sh < 64) ? (a << (sh & 63)) : 0ull;
      hi = (sh == 0) ? 0ull
           : ((sh < 64) ? (a >> ((64 - sh) & 63)) : (a << ((sh - 64) & 63)));
    } else {
      lo = a >> ((-sh) & 63);
      hi = 0ull;
    }
    uint4 wv;
    wv.x = (unsigned)(lo & 0xffffffffull); wv.y = (unsigned)(lo >> 32);
    wv.z = (unsigned)(hi & 0xffffffffull); wv.w = (unsigned)(hi >> 32);
    spl8[(size_t)(bimg * 64 + c) * 4356 + (ih + 1) * 66 + (iw + 1)] = wv;

    trans[iw * 72 + c] = (bf16_t)sl;
  }
  __syncthreads();
  #pragma unroll
  for (int p = 0; p < 2; ++p) {
    int iw2 = (t >> 3) + p * 32;
    int c8  = (t & 7) * 8;
    bf16x8 v = *(const bf16x8*)&trans[iw2 * 72 + c8];
    *(bf16x8*)&silT[((size_t)(bimg * 4356 + (ih + 1) * 66 + (iw2 + 1)) << 6) + c8] = v;
  }
}

// ---------------- border fill: x=0 window / silu 0 (grid-stride, 260 cells) ----------------
__global__ __launch_bounds__(256) void fill_border_kernel(
    uint4* __restrict__ spl8, bf16_t* __restrict__ silT) {
  const int b = blockIdx.x;   // 0..511: spl8 plane ; 512..519: silT image
  for (int s = threadIdx.x; s < 260; s += 256) {
    int ihp, iwp;
    if (s < 66)       { ihp = 0;        iwp = s; }
    else if (s < 132) { ihp = 65;       iwp = s - 66; }
    else if (s < 196) { ihp = s - 131;  iwp = 0; }    // 1..64
    else              { ihp = s - 195;  iwp = 65; }   // 1..64
    if (b < 512) {
      uint4 cw; cw.x = 0u; cw.y = 0x3EF53CABu; cw.z = 0x3CAB3EF5u; cw.w = 0u;
      spl8[(size_t)b * 4356 + ihp * 66 + iwp] = cw;
    } else {
      int img = b - 512;
      uint4 z; z.x = z.y = z.z = z.w = 0u;
      size_t base = ((size_t)(img * 4356 + ihp * 66 + iwp) << 6);
      #pragma unroll
      for (int j = 0; j < 8; ++j)
        *(uint4*)&silT[base + j * 8] = z;
    }
  }
}

// ---------------- main fused GEMM: 2x2 register tile (64px x 64och per wave) ----------------
// block = 1 tile of 64 px (8 oh x 8 ow) x 64 och; 4 waves = 4-way K-split.
// grid 512: 8 img x 8 ohb x 8 owb. 2 blocks/CU -> 8 waves/CU, 256-VGPR budget.
__global__ __launch_bounds__(256, 2) void convkan_kernel(
    const uint4* __restrict__ spl8, const bf16_t* __restrict__ silT,
    const bf16_t* __restrict__ Wf2, float* __restrict__ out) {
  __shared__ float red[3][2][2][32][33];   // 50,688 B

  const int t    = threadIdx.x;
  const int lane = t & 63;
  const int par  = t >> 6;          // K-split 0..3
  const int r    = lane & 31;       // A-row (pixel-in-tile) / B-col (out-ch-in-tile)
  const int kh   = lane >> 5;       // k-half

  const int b  = blockIdx.x;
  const int rb = ((b & 7) << 6) | (b >> 3);   // XCD-chunked: 1 image per XCD
  const int img = rb >> 6;
  const int rem = rb & 63;
  const int ohb = rem >> 3;
  const int owb = rem & 7;

  // padded cell index of pixel (pxt*32 + r) at ki=kj=0
  int arow[2];
  #pragma unroll
  for (int pxt = 0; pxt < 2; ++pxt) {
    int px  = pxt * 32 + r;
    arow[pxt] = (ohb * 8 + (px >> 3)) * 66 + owb * 8 + (px & 7);
  }

  f32x16 acc[2][2];
  #pragma unroll
  for (int a = 0; a < 2; ++a)
    #pragma unroll
    for (int c = 0; c < 2; ++c) acc[a][c] = (f32x16)0.0f;

  // A channel for spline steps: c = par*16 + qq*2 + kh
  const uint4* ac0 = spl8 + ((size_t)(img * 64 + par * 16 + kh)) * 4356;
  // B lane base (elements): o-tile ot adds 512
  const bf16_t* bb = Wf2 + r * 16 + kh * 8;

  for (int qq = 0; qq < 8; ++qq) {
    const uint4*  aq = ac0 + (size_t)qq * 2 * 4356;
    const bf16_t* bq = bb + (size_t)(par * 72 + qq * 9) * 1024;

    bf16x8 Af[2][9];
    bf16x8 Bf[2][9];
    #pragma unroll
    for (int tap = 0; tap < 9; ++tap) {
      const int off = (tap / 3) * 66 + (tap % 3);
      union { uint4 u; bf16x8 v; } A0, A1;
      A0.u = aq[arow[0] + off];
      A1.u = aq[arow[1] + off];
      Af[0][tap] = A0.v;
      Af[1][tap] = A1.v;
      Bf[0][tap] = *(const bf16x8*)(bq + tap * 1024);
      Bf[1][tap] = *(const bf16x8*)(bq + tap * 1024 + 512);
    }
    #pragma unroll
    for (int tap = 0; tap < 9; ++tap) {
      #pragma unroll
      for (int pxt = 0; pxt < 2; ++pxt)
        #pragma unroll
        for (int ot = 0; ot < 2; ++ot)
          acc[pxt][ot] = __builtin_amdgcn_mfma_f32_32x32x16_bf16(
              Af[pxt][tap], Bf[ot][tap], acc[pxt][ot], 0, 0, 0);
    }
  }

  // silu region: this wave handles channel-quad cq = par, taps 0..8
  {
    const int c0 = par * 16 + kh * 8;
    const bf16_t* bq = bb + (size_t)(288 + par * 9) * 1024;
    bf16x8 Af[2][9];
    bf16x8 Bf[2][9];
    #pragma unroll
    for (int tap = 0; tap < 9; ++tap) {
      const int off = (tap / 3) * 66 + (tap % 3);
      #pragma unroll
      for (int pxt = 0; pxt < 2; ++pxt)
        Af[pxt][tap] = *(const bf16x8*)(silT +
            (((size_t)(img * 4356 + arow[pxt] + off)) << 6) + c0);
      Bf[0][tap] = *(const bf16x8*)(bq + tap * 1024);
      Bf[1][tap] = *(const bf16x8*)(bq + tap * 1024 + 512);
    }
    #pragma unroll
    for (int tap = 0; tap < 9; ++tap) {
      #pragma unroll
      for (int pxt = 0; pxt < 2; ++pxt)
        #pragma unroll
        for (int ot = 0; ot < 2; ++ot)
          acc[pxt][ot] = __builtin_amdgcn_mfma_f32_32x32x16_bf16(
              Af[pxt][tap], Bf[ot][tap], acc[pxt][ot], 0, 0, 0);
    }
  }

  // 4-way K-split combine
  if (par != 0) {
    #pragma unroll
    for (int pxt = 0; pxt < 2; ++pxt)
      #pragma unroll
      for (int ot = 0; ot < 2; ++ot)
        #pragma unroll
        for (int q = 0; q < 16; ++q) {
          int ro = (q & 3) + 8 * (q >> 2) + 4 * kh;
          red[par - 1][pxt][ot][ro][r] = acc[pxt][ot][q];
        }
  }
  __syncthreads();
  if (par == 0) {
    #pragma unroll
    for (int pxt = 0; pxt < 2; ++pxt) {
      #pragma unroll
      for (int ot = 0; ot < 2; ++ot) {
        const int o = ot * 32 + r;
        #pragma unroll
        for (int g = 0; g < 4; ++g) {
          const int r0 = 8 * g + 4 * kh;         // row base within 32-tile
          const int px = pxt * 32 + r0;
          float* ob = out + (((size_t)(img * 64 + o)) << 12)
                    + (ohb * 8 + (px >> 3)) * 64 + owb * 8 + (px & 7);
          f32x4 v;
          #pragma unroll
          for (int i = 0; i < 4; ++i) {
            int ro = r0 + i;
            v[i] = acc[pxt][ot][g * 4 + i]
                 + red[0][pxt][ot][ro][r] + red[1][pxt][ot][ro][r]
                 + red[2][pxt][ot][ro][r];
          }
          *(f32x4*)ob = v;
        }
      }
    }
  }
}

extern "C" void kernel_launch(void* const* d_in, const int* in_sizes, int n_in,
                              void* d_out, int out_size, void* d_ws, size_t ws_size,
                              hipStream_t stream) {
  const float* x  = (const float*)d_in[0];
  const float* bw = (const float*)d_in[1];
  const float* sw = (const float*)d_in[2];
  const float* ss = (const float*)d_in[3];

  char* ws = (char*)d_ws;
  bf16_t* Wf2  = (bf16_t*)(ws + WF_OFF);
  uint4*  spl8 = (uint4*)(ws + SPL_OFF);
  bf16_t* silT = (bf16_t*)(ws + SILT_OFF);
  float*  o    = (float*)d_out;

  prep_w_kernel<<<1296, 256, 0, stream>>>(bw, sw, ss, Wf2);
  precomp_kernel<<<512, 256, 0, stream>>>(x, spl8, silT);
  fill_border_kernel<<<520, 256, 0, stream>>>(spl8, silT);
  convkan_kernel<<<512, 256, 0, stream>>>(spl8, silT, Wf2, o);
}

// Round 8
// 56.542 us; speedup vs baseline: 3.8497x; 1.1902x over previous
//
#include <hip/hip_runtime.h>
#include <stdint.h>

typedef __bf16 bf16_t;
typedef __bf16 bf16x8 __attribute__((ext_vector_type(8)));
typedef float  f32x4  __attribute__((ext_vector_type(4)));
typedef float  f32x16 __attribute__((ext_vector_type(16)));

// ws layout
#define WF_OFF    0u
#define SPL_OFF   1048576u                  // 64*8 planes * 4356 cells * 16B = 35,684,352
#define SILT_OFF  (1048576u + 35684352u)    // 8*4356*64*2B = 4,460,544

// async global->LDS, 16B per lane; dest = wave-uniform base + lane*16 (CK idiom)
__device__ __forceinline__ void gld_lds16(const void* g, void* l) {
  __builtin_amdgcn_global_load_lds(
      (const __attribute__((address_space(1))) uint32_t*)g,
      (__attribute__((address_space(3))) uint32_t*)(uintptr_t)l,
      16, 0, 0);
}

// ---------------- weight repack into step-major layout (verified R6/R7) ----------------
// Wf2[s][o][kk], s=0..323, o=0..63, kk=kh*8+j (16 bf16 per (s,o))
// spline steps s = q*9 + tap (q=0..31 channel-pair): c = q*2+kh, f = c*9+tap
// silu steps   s = 288 + cq*9 + tap (cq=0..3): c = cq*16+kk, f = c*9+tap
__global__ __launch_bounds__(256) void prep_w_kernel(
    const float* __restrict__ bw, const float* __restrict__ sw,
    const float* __restrict__ ss, bf16_t* __restrict__ Wf2) {
  int idx = blockIdx.x * 256 + threadIdx.x;   // < 324*64*16 = 331776
  int kk = idx & 15, o = (idx >> 4) & 63, s = idx >> 10;
  int kh = kk >> 3, j = kk & 7;
  float v;
  if (s < 288) {
    int q = s / 9, tap = s - q * 9;
    int c = q * 2 + kh;
    int f = c * 9 + tap;
    v = sw[(o * 576 + f) * 8 + j] * ss[o * 576 + f];
  } else {
    int t2 = s - 288;
    int cq = t2 / 9, tap = t2 - cq * 9;
    int c = cq * 16 + kk;
    int f = c * 9 + tap;
    v = bw[o * 576 + f];
  }
  Wf2[idx] = (bf16_t)v;
}

// ---------------- per-pixel precompute into PADDED layouts (verified) ----------------
__global__ __launch_bounds__(256) void precomp_kernel(
    const float* __restrict__ X, uint4* __restrict__ spl8,
    bf16_t* __restrict__ silT) {
  __shared__ bf16_t trans[64 * 72];
  const int t = threadIdx.x;
  const int bb = blockIdx.x;          // 512: (bimg, ih)
  const int bimg = bb >> 6, ih = bb & 63;
  const int iw = t & 63;
  const int c4 = t >> 6;

  const float* Xp = X + (((size_t)bimg * 64) << 12) + (ih << 6);

  const float G0 = -2.2f, G1 = 2.2f, INVH = 2.5f;

  for (int q = 0; q < 16; ++q) {
    int c = c4 * 16 + q;
    float x = Xp[((size_t)c << 12) + iw];

    float sl = x / (1.0f + __expf(-x));

    float tt = (x - G0) * INVH;
    int i0 = (int)tt;
    i0 = i0 < 0 ? 0 : (i0 > 10 ? 10 : i0);
    float u  = tt - (float)i0;
    float um = 1.0f - u;
    float u2 = u * u, u3 = u2 * u;
    float w0 = um * um * um * (1.0f / 6.0f);
    float w1 = (3.0f * u3 - 6.0f * u2 + 4.0f) * (1.0f / 6.0f);
    float w2 = (-3.0f * u3 + 3.0f * u2 + 3.0f * u + 1.0f) * (1.0f / 6.0f);
    float w3 = u3 * (1.0f / 6.0f);
    bool inr = (x >= G0) & (x < G1);

    union { bf16_t hh4[4]; unsigned long long u64; } pk;
    pk.hh4[0] = (bf16_t)w0; pk.hh4[1] = (bf16_t)w1;
    pk.hh4[2] = (bf16_t)w2; pk.hh4[3] = (bf16_t)w3;
    unsigned long long a = inr ? pk.u64 : 0ull;

    int sh = (i0 - 3) * 16;
    unsigned long long lo, hi;
    if (sh >= 0) {
      lo = (sh < 64) ? (a << (sh & 63)) : 0ull;
      hi = (sh == 0) ? 0ull
           : ((sh < 64) ? (a >> ((64 - sh) & 63)) : (a << ((sh - 64) & 63)));
    } else {
      lo = a >> ((-sh) & 63);
      hi = 0ull;
    }
    uint4 wv;
    wv.x = (unsigned)(lo & 0xffffffffull); wv.y = (unsigned)(lo >> 32);
    wv.z = (unsigned)(hi & 0xffffffffull); wv.w = (unsigned)(hi >> 32);
    spl8[(size_t)(bimg * 64 + c) * 4356 + (ih + 1) * 66 + (iw + 1)] = wv;

    trans[iw * 72 + c] = (bf16_t)sl;
  }
  __syncthreads();
  #pragma unroll
  for (int p = 0; p < 2; ++p) {
    int iw2 = (t >> 3) + p * 32;
    int c8  = (t & 7) * 8;
    bf16x8 v = *(const bf16x8*)&trans[iw2 * 72 + c8];
    *(bf16x8*)&silT[((size_t)(bimg * 4356 + (ih + 1) * 66 + (iw2 + 1)) << 6) + c8] = v;
  }
}

// ---------------- border fill: x=0 window / silu 0 (grid-stride, 260 cells) ----------------
__global__ __launch_bounds__(256) void fill_border_kernel(
    uint4* __restrict__ spl8, bf16_t* __restrict__ silT) {
  const int b = blockIdx.x;   // 0..511: spl8 plane ; 512..519: silT image
  for (int s = threadIdx.x; s < 260; s += 256) {
    int ihp, iwp;
    if (s < 66)       { ihp = 0;        iwp = s; }
    else if (s < 132) { ihp = 65;       iwp = s - 66; }
    else if (s < 196) { ihp = s - 131;  iwp = 0; }    // 1..64
    else              { ihp = s - 195;  iwp = 65; }   // 1..64
    if (b < 512) {
      uint4 cw; cw.x = 0u; cw.y = 0x3EF53CABu; cw.z = 0x3CAB3EF5u; cw.w = 0u;
      spl8[(size_t)b * 4356 + ihp * 66 + iwp] = cw;
    } else {
      int img = b - 512;
      uint4 z; z.x = z.y = z.z = z.w = 0u;
      size_t base = ((size_t)(img * 4356 + ihp * 66 + iwp) << 6);
      #pragma unroll
      for (int j = 0; j < 8; ++j)
        *(uint4*)&silT[base + j * 8] = z;
    }
  }
}

// ---------------- main fused GEMM: full LDS-staged, double-buffered ----------------
// block = 64 px (8x8) x 64 och, 4 waves: (tap-parity tp) x (px-half pw).
// 36 chunks: ci<32 spline (channel-pair ci), ci>=32 silu (quad ci-32).
// Per chunk: A stage 3.2KB + B stage 18KB via global_load_lds (dbuf);
// wave reads 1 A + 2 B frags per tap -> 2 MFMA. 2-way K-reduce epilogue.
__global__ __launch_bounds__(256, 2) void convkan_kernel(
    const uint4* __restrict__ spl8, const bf16_t* __restrict__ silT,
    const bf16_t* __restrict__ Wf2, float* __restrict__ out) {
  __shared__ __align__(16) char smraw[43264];
  uint4* Ast = (uint4*)smraw;               // [2][200]
  uint4* Bst = (uint4*)(smraw + 6400);      // [2][1152]
  float* red = (float*)smraw;               // [2][2][16][64] (epilogue union)

  const int t    = threadIdx.x;
  const int lane = t & 63;
  const int w    = t >> 6;
  const int r    = lane & 31;     // A-row(px) / B-col(och)
  const int kh   = lane >> 5;     // k-half within K=16
  const int pw   = w & 1;         // px-half (0: px 0..31, 1: 32..63)
  const int tp   = w >> 1;        // tap parity

  const int b   = blockIdx.x;
  const int rb  = ((b & 7) << 6) | (b >> 3);   // XCD-chunked (512%8==0, bijective)
  const int img = rb >> 6;
  const int rem = rb & 63;
  const int ohb = rem >> 3, owb = rem & 7;
  const int arow0 = (ohb * 8) * 66 + owb * 8;  // padded cell of block origin

  // ---- staging per-thread precomputes (chunk-independent geometry) ----
  const int tcell = t % 100;                   // cell in 10x10 halo region
  const int tch   = t / 100;                   // channel half (t<200 active)
  const int cellOffS = arow0 + (tcell / 10) * 66 + (tcell % 10);
  const int scell = t >> 1;
  const int scellOff = arow0 + (scell / 10) * 66 + (scell % 10);
  const size_t silBase = (((size_t)(img * 4356 + scellOff)) << 6) + ((t & 1) << 3);

  const int pbase = (pw * 4 + (r >> 3)) * 10 + (r & 7);  // staged cell of px at tap 0

  f32x16 acc0 = (f32x16)0.0f, acc1 = (f32x16)0.0f;

  auto STAGE = [&](int cs, int bb) {
    const bf16_t* bsrc = Wf2 + (size_t)(cs < 32 ? cs * 9 : 288 + (cs - 32) * 9) * 1024;
    uint4* bdst = Bst + bb * 1152 + w * 64;
    #pragma unroll
    for (int rr = 0; rr < 4; ++rr)
      gld_lds16(bsrc + (((size_t)(rr * 256 + t)) << 3), (void*)(bdst + rr * 256));
    if (t < 128)
      gld_lds16(bsrc + (((size_t)(1024 + t)) << 3), (void*)(bdst + 1024));
    if (t < 200) {
      void* adst = (void*)(Ast + bb * 200 + w * 64);
      if (cs < 32)
        gld_lds16(spl8 + (size_t)(img * 64 + 2 * cs + tch) * 4356 + cellOffS, adst);
      else
        gld_lds16(silT + silBase + (size_t)((cs - 32) * 16), adst);
    }
  };

#define TAPBODY(TAP)                                                        \
  {                                                                         \
    int ki = ((TAP) * 11) >> 5;                                             \
    int koff = 10 * ki + ((TAP) - 3 * ki);                                  \
    int cell = pbase + koff;                                                \
    int aunit = spline ? (kh * 100 + cell) : (2 * cell + kh);               \
    bf16x8 Af = *(const bf16x8*)(Ab + aunit);                               \
    const bf16_t* bt = Bb + (TAP) * 1024 + r * 16 + kh * 8;                 \
    bf16x8 B0 = *(const bf16x8*)bt;                                         \
    bf16x8 B1 = *(const bf16x8*)(bt + 512);                                 \
    acc0 = __builtin_amdgcn_mfma_f32_32x32x16_bf16(Af, B0, acc0, 0, 0, 0);  \
    acc1 = __builtin_amdgcn_mfma_f32_32x32x16_bf16(Af, B1, acc1, 0, 0, 0);  \
  }

  STAGE(0, 0);
  __syncthreads();

  int cur = 0;
  for (int ci = 0; ci < 36; ++ci) {
    if (ci < 35) STAGE(ci + 1, cur ^ 1);

    const uint4*  Ab = Ast + cur * 200;
    const bf16_t* Bb = (const bf16_t*)(Bst + cur * 1152);
    const bool spline = (ci < 32);

    #pragma unroll
    for (int i = 0; i < 4; ++i) {
      int tap = 2 * i + tp;    // tp=0: 0,2,4,6 ; tp=1: 1,3,5,7
      TAPBODY(tap);
    }
    if (tp == 0) TAPBODY(8);   // tap 8 (wave-uniform branch)

    __syncthreads();           // drains stage vmcnt + all ds ops, flips buffers
    cur ^= 1;
  }

  // ---- 2-way K-reduce across tap-parity partners, then store ----
  if (tp == 1) {
    #pragma unroll
    for (int q = 0; q < 16; ++q) {
      red[((pw * 2 + 0) * 16 + q) * 64 + lane] = acc0[q];
      red[((pw * 2 + 1) * 16 + q) * 64 + lane] = acc1[q];
    }
  }
  __syncthreads();
  if (tp == 0) {
    #pragma unroll
    for (int ot = 0; ot < 2; ++ot) {
      const int o = ot * 32 + r;
      float* obase = out + (((size_t)(img * 64 + o)) << 12);
      #pragma unroll
      for (int g = 0; g < 4; ++g) {
        f32x4 v;
        #pragma unroll
        for (int iq = 0; iq < 4; ++iq) {
          int q = g * 4 + iq;
          float partner = red[((pw * 2 + ot) * 16 + q) * 64 + lane];
          v[iq] = (ot ? acc1[q] : acc0[q]) + partner;
        }
        int px = pw * 32 + 8 * g + 4 * kh;
        *(f32x4*)(obase + (ohb * 8 + (px >> 3)) * 64 + owb * 8 + (px & 7)) = v;
      }
    }
  }
#undef TAPBODY
}

extern "C" void kernel_launch(void* const* d_in, const int* in_sizes, int n_in,
                              void* d_out, int out_size, void* d_ws, size_t ws_size,
                              hipStream_t stream) {
  const float* x  = (const float*)d_in[0];
  const float* bw = (const float*)d_in[1];
  const float* sw = (const float*)d_in[2];
  const float* ss = (const float*)d_in[3];

  char* ws = (char*)d_ws;
  bf16_t* Wf2  = (bf16_t*)(ws + WF_OFF);
  uint4*  spl8 = (uint4*)(ws + SPL_OFF);
  bf16_t* silT = (bf16_t*)(ws + SILT_OFF);
  float*  o    = (float*)d_out;

  prep_w_kernel<<<1296, 256, 0, stream>>>(bw, sw, ss, Wf2);
  precomp_kernel<<<512, 256, 0, stream>>>(x, spl8, silT);
  fill_border_kernel<<<520, 256, 0, stream>>>(spl8, silT);
  convkan_kernel<<<512, 256, 0, stream>>>(spl8, silT, Wf2, o);
}